// Round 16
// baseline (93.774 us; speedup 1.0000x reference)
//
#include <hip/hip_runtime.h>
#include <hip/hip_bf16.h>

// InfoNCE loss, N=8192 D=512 C=128.
// Fixed-shift softmax (M=10): t_ij = s_ij/tau - 10 in [-20, 0].
//   Z_i  = sum_{class!=} e^{t_ij}
//   term = -t_p + log(Z + e^{t_p}) ~= -t_p + logZ + e^{t_p}/Z
// r15 -> r16: r14 core (i8 MFMA, ring-3, counted vmcnt, conflict-free b128
// swizzle) upgraded to A-SHARED 2-TILE blocks: block = tiles (bi,bj),(bi,bj+1)
// interleaved in the same windows. Per window: stage A+B1+B2 (24KB slot,
// ring-3 = 72KB), 32 MFMA/wave (2x r14) -> the ~1300cy fixed window overhead
// (measured r10/r12/r14/r15) is amortized over twice the math; A ds_reads
// amortized too. vmcnt(6) counted (6 loads/stage, 2 windows in flight),
// NEVER drains mid-loop (r15's drain was the regression). All global stores
// after the loop (r7). 1056 pair-blocks = 8x132 -> exact XCD chunking.
// Odd-row singletons duplicate tile1 in compute, skip its epilogue.
// launch_bounds(256,2): VGPR cap 256 >> ~200 needed (r11/r13 spill lesson).

constexpr int   D      = 512;
constexpr int   BT     = 128;
constexpr int   BK     = 64;         // bytes (i8 elems) per window
constexpr int   NSTEP  = D / BK;     // 8
constexpr float SHIFTL = 14.4269504088896340f;        // 10 * log2(e)
constexpr float QS2L   = 10.0f * 1.4426950408889634f / 16129.0f; // /tau/127^2*log2e
constexpr float LN2    = 0.6931471805599453f;

typedef __attribute__((ext_vector_type(4))) int i32x4;
typedef unsigned char uchar;
typedef unsigned long ulong_t;

__device__ inline void gload_lds16(const uchar* g, void* l) {
    __builtin_amdgcn_global_load_lds(
        (const __attribute__((address_space(1))) void*)g,
        (__attribute__((address_space(3))) void*)l, 16, 0, 0);
}

// ---------------- K1: L2-normalize rows, f32 -> i8 (+hist in block 0) ----
__global__ void k_normalize(const float* __restrict__ emb,
                            const int* __restrict__ classes,
                            uchar* __restrict__ normed,
                            int* __restrict__ hist, int n) {
    if (blockIdx.x == 0) {
        __shared__ int h[128];
        if (threadIdx.x < 128) h[threadIdx.x] = 0;
        __syncthreads();
        for (int i = threadIdx.x; i < n; i += 256)
            atomicAdd(&h[classes[i] & 127], 1);
        __syncthreads();
        if (threadIdx.x < 128) hist[threadIdx.x] = h[threadIdx.x];
    }
    int row  = blockIdx.x * 4 + (threadIdx.x >> 6);
    int lane = threadIdx.x & 63;
    if (row >= n) return;
    const float4* src = (const float4*)(emb + (size_t)row * D);
    float4 a = src[lane * 2];
    float4 b = src[lane * 2 + 1];
    float ss = a.x*a.x + a.y*a.y + a.z*a.z + a.w*a.w
             + b.x*b.x + b.y*b.y + b.z*b.z + b.w*b.w;
#pragma unroll
    for (int m = 1; m < 64; m <<= 1) ss += __shfl_xor(ss, m, 64);
    float sc = 127.0f / fmaxf(sqrtf(ss), 1e-12f);
    union { signed char c[8]; ulong_t u; } o;
    float v[8] = {a.x, a.y, a.z, a.w, b.x, b.y, b.z, b.w};
#pragma unroll
    for (int k = 0; k < 8; ++k) {
        int q = (int)rintf(v[k] * sc);
        q = q > 127 ? 127 : (q < -127 ? -127 : q);
        o.c[k] = (signed char)q;
    }
    *(ulong_t*)&normed[(size_t)row * D + lane * 8] = o.u;
}

// ---------------- K2: A-shared 2-tile i8 GEMM, ring-3, vmcnt(6) -----------
// Zpart: plane q in 0..2 (Z,NS2,P1), each [64 slots][n rows].
__global__ __launch_bounds__(256, 2) void k_zgemm(
    const uchar* __restrict__ normed, const int* __restrict__ classes,
    float* __restrict__ Zpart, int n, int nblk) {
    __shared__ char ring[3][24576];           // 72 KB: slot = A|B1|B2 x 8KB
    __shared__ int clsrow[BT], clscol1[BT], clscol2[BT];

    const int tid  = threadIdx.x;
    const int lane = tid & 63;
    const int w    = tid >> 6;
    const int wm   = w >> 1, wn = w & 1;
    const int l15  = lane & 15, l4 = lane >> 4;
    const size_t QS = (size_t)64 * n;

    // XCD-chunked bijective swizzle (nblk = 1056 = 8*132)
    int q8 = nblk >> 3, r8 = nblk & 7;
    int xcd = blockIdx.x & 7, off = blockIdx.x >> 3;
    int orig = (xcd < r8 ? xcd * (q8 + 1) : r8 * (q8 + 1) + (xcd - r8) * q8) + off;

    // decode: rows bi 0..63, row bi has ceil((64-bi)/2) pair-blocks
    int idx = orig, bi = 0;
    for (;;) { int npb = (64 - bi + 1) >> 1; if (idx < npb) break; idx -= npb; ++bi; }
    const int  bj1    = bi + idx * 2;
    const bool valid2 = (bj1 + 1 < 64);
    const int  bj2    = valid2 ? bj1 + 1 : bj1;
    const int  row0 = bi * BT, c01 = bj1 * BT, c02 = bj2 * BT;
    const bool diag1 = (bj1 == bi);

    if (tid < BT) {
        clsrow[tid]  = classes[row0 + tid];
        clscol2[tid] = classes[c02 + tid];
    } else {
        clscol1[tid - BT] = classes[c01 + tid - BT];
    }
    int crow[16];
#pragma unroll
    for (int t = 0; t < 16; ++t)
        crow[t] = classes[row0 + wm * 64 + (t >> 2) * 16 + l4 * 4 + (t & 3)];

    // staging: chunk = 16 rows x 64B (1KB); wave w owns chunks {2w,2w+1} of
    // each matrix. Source 16B slot pre-swizzled (involution, r10-proven).
    const int src16 = (lane & 3) ^ ((lane >> 3) & 3);
    size_t gA[2], gB1[2], gB2[2]; int lo[2];
#pragma unroll
    for (int it = 0; it < 2; ++it) {
        int chunk = w * 2 + it;
        int row   = chunk * 16 + (lane >> 2);
        gA[it]  = (size_t)(row0 + row) * D + src16 * 16;
        gB1[it] = (size_t)(c01  + row) * D + src16 * 16;
        gB2[it] = (size_t)(c02  + row) * D + src16 * 16;
        lo[it]  = chunk * 1024;
    }
    char* ringb = &ring[0][0];

    auto STAGE = [&](int sbo, int kk) {       // kk = window * 64 (bytes)
#pragma unroll
        for (int it = 0; it < 2; ++it) {
            gload_lds16(normed + gA[it]  + kk, ringb + sbo + lo[it]);
            gload_lds16(normed + gB1[it] + kk, ringb + sbo + 8192  + lo[it]);
            gload_lds16(normed + gB2[it] + kk, ringb + sbo + 16384 + lo[it]);
        }
    };

    i32x4 acc[2][4][4];
#pragma unroll
    for (int t = 0; t < 2; ++t)
#pragma unroll
        for (int a = 0; a < 4; ++a)
#pragma unroll
            for (int b = 0; b < 4; ++b) acc[t][a][b] = (i32x4){0, 0, 0, 0};

    STAGE(0, 0);
    STAGE(24576, BK);
    __builtin_amdgcn_sched_barrier(0);
    asm volatile("s_waitcnt vmcnt(6) lgkmcnt(0)" ::: "memory");
    __builtin_amdgcn_s_barrier();
    __builtin_amdgcn_sched_barrier(0);

    // b128 read: 16B slot = l4 ^ ((l15>>1)&3)  (conflict-free, r10-measured)
    const int rsw = (l15 >> 1) & 3;

#pragma unroll
    for (int kt = 0; kt < NSTEP; ++kt) {
        const int cur = kt % 3;
        if (kt + 2 < NSTEP) STAGE(((kt + 2) % 3) * 24576, (kt + 2) * BK);
        const char* la  = ringb + cur * 24576;
        const char* lb1 = la + 8192;
        const char* lb2 = la + 16384;
        i32x4 af[4], b1[4], b2[4];
#pragma unroll
        for (int mf = 0; mf < 4; ++mf) {
            int ra = wm * 64 + mf * 16 + l15;
            af[mf] = *(const i32x4*)(la + ra * 64 + ((l4 ^ rsw) << 4));
        }
#pragma unroll
        for (int nf = 0; nf < 4; ++nf) {
            int rb = wn * 64 + nf * 16 + l15;
            int ro = rb * 64 + ((l4 ^ rsw) << 4);
            b1[nf] = *(const i32x4*)(lb1 + ro);
            b2[nf] = *(const i32x4*)(lb2 + ro);
        }
        __builtin_amdgcn_s_setprio(1);
#pragma unroll
        for (int mf = 0; mf < 4; ++mf)
#pragma unroll
            for (int nf = 0; nf < 4; ++nf) {
                acc[0][mf][nf] = __builtin_amdgcn_mfma_i32_16x16x64_i8(
                    af[mf], b1[nf], acc[0][mf][nf], 0, 0, 0);
                acc[1][mf][nf] = __builtin_amdgcn_mfma_i32_16x16x64_i8(
                    af[mf], b2[nf], acc[1][mf][nf], 0, 0, 0);
            }
        __builtin_amdgcn_s_setprio(0);
        __builtin_amdgcn_sched_barrier(0);
        if (kt + 2 < NSTEP)       asm volatile("s_waitcnt vmcnt(6)" ::: "memory");
        else if (kt + 2 == NSTEP) asm volatile("s_waitcnt vmcnt(0)" ::: "memory");
        if (kt + 1 < NSTEP) {
            __builtin_amdgcn_s_barrier();
            __builtin_amdgcn_sched_barrier(0);
        }
    }
    __syncthreads();   // full drain before LDS overlay

    // ---- per-tile epilogues (exp2 domain), all global stores post-loop ----
    float* redr = (float*)ringb;              // [2(wn)][128][3] = 3 KB
    float* redc = (float*)(ringb + 8192);     // [2(wm)][128][3] = 3 KB

#pragma unroll
    for (int t = 0; t < 2; ++t) {
        if (t == 1 && !valid2) break;         // block-uniform
        const int  c0t   = t ? c02 : c01;
        const int  bjt   = t ? bj2 : bj1;
        const int* clsc  = t ? clscol2 : clscol1;
        const bool dgblk = (t == 0) && diag1;

        float cqz[4] = {0,0,0,0}, cqn[4] = {0,0,0,0}, cqp[4] = {0,0,0,0};
#pragma unroll
        for (int mf = 0; mf < 4; ++mf) {
#pragma unroll
            for (int r = 0; r < 4; ++r) {
                int rr = wm * 64 + mf * 16 + l4 * 4 + r;
                int cr = crow[mf * 4 + r];
                float z = 0.f, ns = 0.f, p1 = 0.f;
#pragma unroll
                for (int nf = 0; nf < 4; ++nf) {
                    int cc = wn * 64 + nf * 16 + l15;
                    float tt = fmaf((float)acc[t][mf][nf][r], QS2L, -SHIFTL);
                    float e = exp2f(tt);
                    bool same = (cr == clsc[cc]);
                    bool dg   = dgblk && (rr == cc);
                    if (!same) { z += e; cqz[nf] += e; }
                    else if (!dg) { ns += tt; p1 += e; cqn[nf] += tt; cqp[nf] += e; }
                }
#pragma unroll
                for (int m = 1; m < 16; m <<= 1) {
                    z  += __shfl_xor(z,  m, 16);
                    ns += __shfl_xor(ns, m, 16);
                    p1 += __shfl_xor(p1, m, 16);
                }
                if (l15 == 0) {
                    float* p = &redr[(wn * 128 + rr) * 3];
                    p[0] = z; p[1] = ns; p[2] = p1;
                }
            }
        }
        if (!dgblk) {
#pragma unroll
            for (int nf = 0; nf < 4; ++nf) {
                float z = cqz[nf], nsv = cqn[nf], p = cqp[nf];
                z += __shfl_xor(z, 16, 64);  z += __shfl_xor(z, 32, 64);
                nsv += __shfl_xor(nsv, 16, 64); nsv += __shfl_xor(nsv, 32, 64);
                p += __shfl_xor(p, 16, 64);  p += __shfl_xor(p, 32, 64);
                if (l4 == 0) {
                    float* pp = &redc[(wm * 128 + wn * 64 + nf * 16 + l15) * 3];
                    pp[0] = z; pp[1] = nsv; pp[2] = p;
                }
            }
        }
        __syncthreads();

        if (tid < BT) {                       // row-side partials, slot = bjt
#pragma unroll
            for (int q = 0; q < 3; ++q)
                Zpart[q * QS + (size_t)bjt * n + row0 + tid] =
                    redr[(0 * 128 + tid) * 3 + q] + redr[(1 * 128 + tid) * 3 + q];
        } else if (!dgblk) {                  // col-side partials, slot = bi
            int cc = tid - BT;
#pragma unroll
            for (int q = 0; q < 3; ++q)
                Zpart[q * QS + (size_t)bi * n + c0t + cc] =
                    redc[(0 * 128 + cc) * 3 + q] + redc[(1 * 128 + cc) * 3 + q];
        }
        __syncthreads();                      // LDS reads done before reuse
    }
}

// ---------------- K3: per-row closed-form terms ----------------
__global__ void k_rowterms(const float* __restrict__ Zpart,
                           const int* __restrict__ classes,
                           const int* __restrict__ hist,
                           float* __restrict__ rowloss,
                           float* __restrict__ rowcnt, int n) {
    int i = blockIdx.x * 256 + threadIdx.x;
    if (i >= n) return;
    const size_t QS = (size_t)64 * n;
    float z = 0.f, ns = 0.f, p1 = 0.f;
    for (int s = 0; s < 64; ++s) {
        size_t o = (size_t)s * n + i;
        z  += Zpart[o];
        ns += Zpart[QS + o];
        p1 += Zpart[2 * QS + o];
    }
    float c = (float)(hist[classes[i] & 127] - 1);
    rowloss[i] = -ns * LN2 + c * logf(z) + p1 / z;   // ns was in log2 units
    rowcnt[i]  = c;
}

// ---------------- K4: final deterministic reduction ----------------
__global__ void k_final(const float* __restrict__ rowloss,
                        const float* __restrict__ rowcnt,
                        float* __restrict__ out, int n) {
    __shared__ float sl[1024];
    __shared__ float sc[1024];
    float l = 0.f, c = 0.f;
    for (int i = threadIdx.x; i < n; i += 1024) {
        l += rowloss[i];
        c += rowcnt[i];
    }
    sl[threadIdx.x] = l;
    sc[threadIdx.x] = c;
    __syncthreads();
    for (int s = 512; s > 0; s >>= 1) {
        if (threadIdx.x < s) {
            sl[threadIdx.x] += sl[threadIdx.x + s];
            sc[threadIdx.x] += sc[threadIdx.x + s];
        }
        __syncthreads();
    }
    if (threadIdx.x == 0)
        out[0] = (sc[0] > 0.f) ? sl[0] / sc[0] : 0.f;
}

extern "C" void kernel_launch(void* const* d_in, const int* in_sizes, int n_in,
                              void* d_out, int out_size, void* d_ws, size_t ws_size,
                              hipStream_t stream) {
    const float* emb     = (const float*)d_in[0];
    const int*   classes = (const int*)d_in[1];
    float*       out     = (float*)d_out;
    const int n = in_sizes[1];                // 8192
    const int nblk = 1056;                    // sum_{bi} ceil((64-bi)/2)

    uchar*  normed  = (uchar*)d_ws;                                    // 4 MB
    float*  Zpart   = (float*)((char*)d_ws + (size_t)n * D);           // 6 MB
    float*  rowloss = Zpart + (size_t)3 * 64 * n;
    float*  rowcnt  = rowloss + n;
    int*    hist    = (int*)(rowcnt + n);                              // 512 B

    k_normalize<<<n / 4, 256, 0, stream>>>(emb, classes, normed, hist, n);
    k_zgemm<<<nblk, 256, 0, stream>>>(normed, classes, Zpart, n, nblk);
    k_rowterms<<<(n + 255) / 256, 256, 0, stream>>>(Zpart, classes, hist, rowloss, rowcnt, n);
    k_final<<<1, 1024, 0, stream>>>(rowloss, rowcnt, out, n);
}

// Round 17
// 86.455 us; speedup vs baseline: 1.0847x; 1.0847x over previous
//
#include <hip/hip_runtime.h>
#include <hip/hip_bf16.h>

// InfoNCE loss, N=8192 D=512 C=128.
// Fixed-shift softmax (M=10): t_ij = s_ij/tau - 10 in [-20, 0].
//   Z_i  = sum_{class!=} e^{t_ij}
//   term = -t_p + log(Z + e^{t_p}) ~= -t_p + logZ + e^{t_p}/Z
// r16 -> r17: BARRIER-FREE K-loop. r14's limiter was the per-window sync
// chain (~1950cy/window vs 320cy MFMA; barrier convoy kept resident blocks
// from overlapping -> MfmaUtil 12%). New structure: A strip in REGISTERS
// (wave w owns rows w*32..+32; areg[2][8] = 64 VGPR, all compile-time
// indices), B tile (128x512 i8 = 64KB) staged to LDS ONCE with col-XOR
// swizzle (phys = logical ^ (col&7), 2-way = free; pre-swizzled global
// source, linear dest). K-loop = 64 ds_read_b128 + 128 i8-MFMA per wave,
// ZERO barriers, ZERO inline asm (compiler lgkmcnt scheduling, m97).
// 2 blocks/CU; 16 independent 8-deep MFMA chains. Same supertile+XCD walk,
// same Zpart slot scheme, exp2-domain epilogue. All stores post-loop.

constexpr int   D      = 512;
constexpr int   BT     = 128;
constexpr float SHIFTL = 14.4269504088896340f;        // 10 * log2(e)
constexpr float QS2L   = 10.0f * 1.4426950408889634f / 16129.0f; // /tau/127^2*log2e
constexpr float LN2    = 0.6931471805599453f;

typedef __attribute__((ext_vector_type(4))) int i32x4;
typedef unsigned char uchar;
typedef unsigned long ulong_t;

__device__ inline void gload_lds16(const uchar* g, void* l) {
    __builtin_amdgcn_global_load_lds(
        (const __attribute__((address_space(1))) void*)g,
        (__attribute__((address_space(3))) void*)l, 16, 0, 0);
}

// ---------------- K1: L2-normalize rows, f32 -> i8 (+hist in block 0) ----
__global__ void k_normalize(const float* __restrict__ emb,
                            const int* __restrict__ classes,
                            uchar* __restrict__ normed,
                            int* __restrict__ hist, int n) {
    if (blockIdx.x == 0) {
        __shared__ int h[128];
        if (threadIdx.x < 128) h[threadIdx.x] = 0;
        __syncthreads();
        for (int i = threadIdx.x; i < n; i += 256)
            atomicAdd(&h[classes[i] & 127], 1);
        __syncthreads();
        if (threadIdx.x < 128) hist[threadIdx.x] = h[threadIdx.x];
    }
    int row  = blockIdx.x * 4 + (threadIdx.x >> 6);
    int lane = threadIdx.x & 63;
    if (row >= n) return;
    const float4* src = (const float4*)(emb + (size_t)row * D);
    float4 a = src[lane * 2];
    float4 b = src[lane * 2 + 1];
    float ss = a.x*a.x + a.y*a.y + a.z*a.z + a.w*a.w
             + b.x*b.x + b.y*b.y + b.z*b.z + b.w*b.w;
#pragma unroll
    for (int m = 1; m < 64; m <<= 1) ss += __shfl_xor(ss, m, 64);
    float sc = 127.0f / fmaxf(sqrtf(ss), 1e-12f);
    union { signed char c[8]; ulong_t u; } o;
    float v[8] = {a.x, a.y, a.z, a.w, b.x, b.y, b.z, b.w};
#pragma unroll
    for (int k = 0; k < 8; ++k) {
        int q = (int)rintf(v[k] * sc);
        q = q > 127 ? 127 : (q < -127 ? -127 : q);
        o.c[k] = (signed char)q;
    }
    *(ulong_t*)&normed[(size_t)row * D + lane * 8] = o.u;
}

// ---------------- K2: barrier-free i8 GEMM (A in regs, B in LDS) ----------
// Zpart: plane q in 0..2 (Z,NS2,P1), each [64 slots][n rows].
__global__ __launch_bounds__(256, 2) void k_zgemm(
    const uchar* __restrict__ normed, const int* __restrict__ classes,
    float* __restrict__ Zpart, int n, int nb, int npairs) {
    __shared__ char Blds[65536];              // B tile: [col 128][512 B] swizzled
    __shared__ int clsrow[BT], clscol[BT];

    const int tid  = threadIdx.x;
    const int lane = tid & 63;
    const int w    = tid >> 6;                // 0..3; wave owns rows w*32..+32
    const int l15  = lane & 15, l4 = lane >> 4;
    const size_t QS = (size_t)64 * n;

    // XCD-chunked bijective swizzle
    int q8 = npairs >> 3, r8 = npairs & 7;
    int xcd = blockIdx.x & 7, off = blockIdx.x >> 3;
    int orig = (xcd < r8 ? xcd * (q8 + 1) : r8 * (q8 + 1) + (xcd - r8) * q8) + off;

    // orig -> (bi,bj) via 8x8 supertile walk (2D locality within an XCD)
    const int sgrid = nb >> 3;               // 8
    int idx = orig, si = 0;
    for (;;) { int rc = 36 + (sgrid - 1 - si) * 64; if (idx < rc) break; idx -= rc; ++si; }
    int bi, bj;
    if (idx < 36) { int u = 0, rem = 8; while (idx >= rem) { idx -= rem; ++u; --rem; }
                    bi = si * 8 + u; bj = si * 8 + u + idx; }
    else { idx -= 36; int sj = si + 1 + (idx >> 6); int v = idx & 63;
           bi = si * 8 + (v >> 3); bj = sj * 8 + (v & 7); }
    const int row0 = bi * BT, c0 = bj * BT;
    const bool diagblk = (bi == bj);

    if (tid < BT) clsrow[tid] = classes[row0 + tid];
    else          clscol[tid - BT] = classes[c0 + tid - BT];

    // per-lane class registers for the epilogue
    int crow[2][4];
#pragma unroll
    for (int rg = 0; rg < 2; ++rg)
#pragma unroll
        for (int r = 0; r < 4; ++r)
            crow[rg][r] = classes[row0 + w * 32 + rg * 16 + l4 * 4 + r];
    int ccv[8];
#pragma unroll
    for (int cf = 0; cf < 8; ++cf)
        ccv[cf] = classes[c0 + cf * 16 + l15];

    // ---- A strip into registers: areg[rg][kf] ----
    // lane: row = row0 + w*32 + rg*16 + l15, k-bytes [kf*64 + l4*16, +16)
    i32x4 areg[2][8];
#pragma unroll
    for (int rg = 0; rg < 2; ++rg)
#pragma unroll
        for (int kf = 0; kf < 8; ++kf)
            areg[rg][kf] = *(const i32x4*)&normed[
                (size_t)(row0 + w * 32 + rg * 16 + l15) * D + kf * 64 + l4 * 16];

    // ---- B tile staged once, col-XOR swizzled ----
    // round rr: cols [rr*8, rr*8+8); wave w covers cols rr*8 + w*2 + (lane>>5).
    // dest = (rr*8 + w*2)*512 + lane*16 (linear, wave-uniform base).
    // phys 16B-slot p = lane&31 holds logical slot p ^ (col&7)  (involution).
    {
        const int colw = w * 2 + (lane >> 5);
        const int p    = lane & 31;
#pragma unroll
        for (int rr = 0; rr < 16; ++rr) {
            int col = rr * 8 + colw;
            gload_lds16(&normed[(size_t)(c0 + col) * D + ((p ^ (col & 7)) << 4)],
                        Blds + (rr * 8 + w * 2) * 512 + lane * 16);
        }
    }
    __syncthreads();      // drains vmcnt(0) lgkmcnt(0): A regs + B LDS ready

    // ---- barrier-free K-loop: 64 ds_read + 128 MFMA, 16 indep chains ----
    i32x4 acc[2][8];
#pragma unroll
    for (int rg = 0; rg < 2; ++rg)
#pragma unroll
        for (int cf = 0; cf < 8; ++cf) acc[rg][cf] = (i32x4){0, 0, 0, 0};

    const int csw = l15 & 7;                  // col&7 for this lane's cols
#pragma unroll
    for (int kf = 0; kf < 8; ++kf) {
#pragma unroll
        for (int cf = 0; cf < 8; ++cf) {
            int cc = cf * 16 + l15;
            i32x4 bf = *(const i32x4*)(Blds + cc * 512 +
                        (((kf * 4 + l4) ^ csw) << 4));
            acc[0][cf] = __builtin_amdgcn_mfma_i32_16x16x64_i8(
                areg[0][kf], bf, acc[0][cf], 0, 0, 0);
            acc[1][cf] = __builtin_amdgcn_mfma_i32_16x16x64_i8(
                areg[1][kf], bf, acc[1][cf], 0, 0, 0);
        }
    }
    __syncthreads();      // all B reads done -> safe to overlay

    // ---- epilogue (exp2 domain): overlay scratch in B space ----
    float* redc = (float*)Blds;               // [4 w][128 cc][3] = 6 KB
    float* redr = (float*)(Blds + 8192);      // [128 rr][3] = 1.5 KB

    float cq[8][3];
#pragma unroll
    for (int cf = 0; cf < 8; ++cf) cq[cf][0] = cq[cf][1] = cq[cf][2] = 0.f;

#pragma unroll
    for (int rg = 0; rg < 2; ++rg) {
#pragma unroll
        for (int r = 0; r < 4; ++r) {
            int rr = w * 32 + rg * 16 + l4 * 4 + r;
            int cr = crow[rg][r];
            float z = 0.f, ns = 0.f, p1 = 0.f;
#pragma unroll
            for (int cf = 0; cf < 8; ++cf) {
                int cc = cf * 16 + l15;
                float tt = fmaf((float)acc[rg][cf][r], QS2L, -SHIFTL);
                float e = exp2f(tt);
                bool same = (cr == ccv[cf]);
                bool dg   = diagblk && (rr == cc);
                if (!same) { z += e; cq[cf][0] += e; }
                else if (!dg) { ns += tt; p1 += e; cq[cf][1] += tt; cq[cf][2] += e; }
            }
#pragma unroll
            for (int m = 1; m < 16; m <<= 1) {
                z  += __shfl_xor(z,  m, 16);
                ns += __shfl_xor(ns, m, 16);
                p1 += __shfl_xor(p1, m, 16);
            }
            if (l15 == 0) {
                redr[rr * 3 + 0] = z;
                redr[rr * 3 + 1] = ns;
                redr[rr * 3 + 2] = p1;
            }
        }
    }
    if (!diagblk) {
#pragma unroll
        for (int cf = 0; cf < 8; ++cf) {
            float z = cq[cf][0], nsv = cq[cf][1], p = cq[cf][2];
            z += __shfl_xor(z, 16, 64);  z += __shfl_xor(z, 32, 64);
            nsv += __shfl_xor(nsv, 16, 64); nsv += __shfl_xor(nsv, 32, 64);
            p += __shfl_xor(p, 16, 64);  p += __shfl_xor(p, 32, 64);
            if (l4 == 0) {
                float* pp = &redc[(w * 128 + cf * 16 + l15) * 3];
                pp[0] = z; pp[1] = nsv; pp[2] = p;
            }
        }
    }
    __syncthreads();

    if (tid < BT) {                           // row-side partials, slot = bj
#pragma unroll
        for (int q = 0; q < 3; ++q)
            Zpart[q * QS + (size_t)bj * n + row0 + tid] = redr[tid * 3 + q];
    } else if (!diagblk) {                    // col-side partials, slot = bi
        int cc = tid - BT;
#pragma unroll
        for (int q = 0; q < 3; ++q)
            Zpart[q * QS + (size_t)bi * n + c0 + cc] =
                redc[(0 * 128 + cc) * 3 + q] + redc[(1 * 128 + cc) * 3 + q] +
                redc[(2 * 128 + cc) * 3 + q] + redc[(3 * 128 + cc) * 3 + q];
    }
}

// ---------------- K3: per-row closed-form terms ----------------
__global__ void k_rowterms(const float* __restrict__ Zpart,
                           const int* __restrict__ classes,
                           const int* __restrict__ hist,
                           float* __restrict__ rowloss,
                           float* __restrict__ rowcnt, int n) {
    int i = blockIdx.x * 256 + threadIdx.x;
    if (i >= n) return;
    const size_t QS = (size_t)64 * n;
    float z = 0.f, ns = 0.f, p1 = 0.f;
    for (int s = 0; s < 64; ++s) {
        size_t o = (size_t)s * n + i;
        z  += Zpart[o];
        ns += Zpart[QS + o];
        p1 += Zpart[2 * QS + o];
    }
    float c = (float)(hist[classes[i] & 127] - 1);
    rowloss[i] = -ns * LN2 + c * logf(z) + p1 / z;   // ns was in log2 units
    rowcnt[i]  = c;
}

// ---------------- K4: final deterministic reduction ----------------
__global__ void k_final(const float* __restrict__ rowloss,
                        const float* __restrict__ rowcnt,
                        float* __restrict__ out, int n) {
    __shared__ float sl[1024];
    __shared__ float sc[1024];
    float l = 0.f, c = 0.f;
    for (int i = threadIdx.x; i < n; i += 1024) {
        l += rowloss[i];
        c += rowcnt[i];
    }
    sl[threadIdx.x] = l;
    sc[threadIdx.x] = c;
    __syncthreads();
    for (int s = 512; s > 0; s >>= 1) {
        if (threadIdx.x < s) {
            sl[threadIdx.x] += sl[threadIdx.x + s];
            sc[threadIdx.x] += sc[threadIdx.x + s];
        }
        __syncthreads();
    }
    if (threadIdx.x == 0)
        out[0] = (sc[0] > 0.f) ? sl[0] / sc[0] : 0.f;
}

extern "C" void kernel_launch(void* const* d_in, const int* in_sizes, int n_in,
                              void* d_out, int out_size, void* d_ws, size_t ws_size,
                              hipStream_t stream) {
    const float* emb     = (const float*)d_in[0];
    const int*   classes = (const int*)d_in[1];
    float*       out     = (float*)d_out;
    const int n  = in_sizes[1];               // 8192
    const int nb = n / BT;                    // 64
    const int npairs = nb * (nb + 1) / 2;     // 2080

    uchar*  normed  = (uchar*)d_ws;                                    // 4 MB
    float*  Zpart   = (float*)((char*)d_ws + (size_t)n * D);           // 6 MB
    float*  rowloss = Zpart + (size_t)3 * 64 * n;
    float*  rowcnt  = rowloss + n;
    int*    hist    = (int*)(rowcnt + n);                              // 512 B

    k_normalize<<<n / 4, 256, 0, stream>>>(emb, classes, normed, hist, n);
    k_zgemm<<<npairs, 256, 0, stream>>>(normed, classes, Zpart, n, nb, npairs);
    k_rowterms<<<(n + 255) / 256, 256, 0, stream>>>(Zpart, classes, hist, rowloss, rowcnt, n);
    k_final<<<1, 1024, 0, stream>>>(rowloss, rowcnt, out, n);
}

// Round 18
// 81.563 us; speedup vs baseline: 1.1497x; 1.0600x over previous
//
#include <hip/hip_runtime.h>
#include <hip/hip_bf16.h>

// InfoNCE loss, N=8192 D=512 C=128.
// Fixed-shift softmax (M=10): t_ij = s_ij/tau - 10 in [-20, 0].
//   Z_i  = sum_{class!=} e^{t_ij}
//   term = -t_p + log(Z + e^{t_p}) ~= -t_p + logZ + e^{t_p}/Z
// r17 -> r18: CONSOLIDATE. Five structural zgemm variants (r12/r13/r15/r16/
// r17) all lost to r14's ring-3 + counted-vmcnt + i8 core -> revert to r14
// VERBATIM (52.8us, VGPR 72, 0 bank conflicts, FETCH 10.6MB). Attack the
// ~23us tail instead: fuse k_rowterms + k_final via deterministic last-block
// reduction (ticket atomicAdd + threadfence; last block reduces the 32
// partials in fixed order) -- kills k_final's ~7us single-block latency and
// one launch. Counter zeroed with hipMemsetAsync (graph-safe).

constexpr int   D      = 512;
constexpr int   BT     = 128;
constexpr int   BK     = 64;         // bytes (i8 elems) per window
constexpr int   NSTEP  = D / BK;     // 8
constexpr float SHIFTL = 14.4269504088896340f;        // 10 * log2(e)
constexpr float QS2L   = 10.0f * 1.4426950408889634f / 16129.0f; // /tau/127^2*log2e
constexpr float LN2    = 0.6931471805599453f;

typedef __attribute__((ext_vector_type(4))) int i32x4;
typedef unsigned char uchar;
typedef unsigned long ulong_t;

__device__ inline void gload_lds16(const uchar* g, void* l) {
    __builtin_amdgcn_global_load_lds(
        (const __attribute__((address_space(1))) void*)g,
        (__attribute__((address_space(3))) void*)l, 16, 0, 0);
}

// ---------------- K1: L2-normalize rows, f32 -> i8 (+hist in block 0) ----
__global__ void k_normalize(const float* __restrict__ emb,
                            const int* __restrict__ classes,
                            uchar* __restrict__ normed,
                            int* __restrict__ hist, int n) {
    if (blockIdx.x == 0) {
        __shared__ int h[128];
        if (threadIdx.x < 128) h[threadIdx.x] = 0;
        __syncthreads();
        for (int i = threadIdx.x; i < n; i += 256)
            atomicAdd(&h[classes[i] & 127], 1);
        __syncthreads();
        if (threadIdx.x < 128) hist[threadIdx.x] = h[threadIdx.x];
    }
    int row  = blockIdx.x * 4 + (threadIdx.x >> 6);
    int lane = threadIdx.x & 63;
    if (row >= n) return;
    const float4* src = (const float4*)(emb + (size_t)row * D);
    float4 a = src[lane * 2];
    float4 b = src[lane * 2 + 1];
    float ss = a.x*a.x + a.y*a.y + a.z*a.z + a.w*a.w
             + b.x*b.x + b.y*b.y + b.z*b.z + b.w*b.w;
#pragma unroll
    for (int m = 1; m < 64; m <<= 1) ss += __shfl_xor(ss, m, 64);
    float sc = 127.0f / fmaxf(sqrtf(ss), 1e-12f);
    union { signed char c[8]; ulong_t u; } o;
    float v[8] = {a.x, a.y, a.z, a.w, b.x, b.y, b.z, b.w};
#pragma unroll
    for (int k = 0; k < 8; ++k) {
        int q = (int)rintf(v[k] * sc);
        q = q > 127 ? 127 : (q < -127 ? -127 : q);
        o.c[k] = (signed char)q;
    }
    *(ulong_t*)&normed[(size_t)row * D + lane * 8] = o.u;
}

// ---------------- K2: symmetric masked-exp i8 GEMM, ring-3 (r14) ----------
// Zpart: plane q in 0..2 (Z,NS2,P1), each [64 slots][n rows].
__global__ __launch_bounds__(256, 3) void k_zgemm(
    const uchar* __restrict__ normed, const int* __restrict__ classes,
    float* __restrict__ Zpart, int n, int nb, int npairs) {
    __shared__ char ring[3][16384];           // 3 units x (A 8KB | B 8KB)
    __shared__ int clsrow[BT], clscol[BT];

    const int tid  = threadIdx.x;
    const int lane = tid & 63;
    const int w    = tid >> 6;
    const int wm   = w >> 1, wn = w & 1;
    const int l15  = lane & 15, l4 = lane >> 4;
    const size_t QS = (size_t)64 * n;

    // XCD-chunked bijective swizzle
    int q8 = npairs >> 3, r8 = npairs & 7;
    int xcd = blockIdx.x & 7, off = blockIdx.x >> 3;
    int orig = (xcd < r8 ? xcd * (q8 + 1) : r8 * (q8 + 1) + (xcd - r8) * q8) + off;

    // orig -> (bi,bj) via 8x8 supertile walk (2D locality within an XCD)
    const int sgrid = nb >> 3;               // 8
    int idx = orig, si = 0;
    for (;;) { int rc = 36 + (sgrid - 1 - si) * 64; if (idx < rc) break; idx -= rc; ++si; }
    int bi, bj;
    if (idx < 36) { int u = 0, rem = 8; while (idx >= rem) { idx -= rem; ++u; --rem; }
                    bi = si * 8 + u; bj = si * 8 + u + idx; }
    else { idx -= 36; int sj = si + 1 + (idx >> 6); int v = idx & 63;
           bi = si * 8 + (v >> 3); bj = sj * 8 + (v & 7); }
    const int row0 = bi * BT, c0 = bj * BT;
    const bool diagblk = (bi == bj);

    if (tid < BT) clsrow[tid] = classes[row0 + tid];
    else          clscol[tid - BT] = classes[c0 + tid - BT];
    int crow[16];
#pragma unroll
    for (int t = 0; t < 16; ++t)
        crow[t] = classes[row0 + wm * 64 + (t >> 2) * 16 + l4 * 4 + (t & 3)];

    // staging: chunk = 16 rows x 64B (1KB). wave w owns chunks {2w,2w+1}.
    // lane l: row = chunk*16 + (l>>2); LDS dst = base + lane*16 (linear).
    // 16B source slot pre-swizzled: src16 = (l&3) ^ ((l>>3)&3) (involution).
    const int src16 = (lane & 3) ^ ((lane >> 3) & 3);
    size_t gA[2], gB[2]; int lo[2];
#pragma unroll
    for (int it = 0; it < 2; ++it) {
        int chunk = w * 2 + it;
        int row   = chunk * 16 + (lane >> 2);
        gA[it] = (size_t)(row0 + row) * D + src16 * 16;
        gB[it] = (size_t)(c0   + row) * D + src16 * 16;
        lo[it] = chunk * 1024;
    }
    char* ringb = &ring[0][0];

    auto STAGE = [&](int sbo, int kk) {       // kk = unit * 64 (bytes)
#pragma unroll
        for (int it = 0; it < 2; ++it) {
            gload_lds16(normed + gA[it] + kk, ringb + sbo + lo[it]);
            gload_lds16(normed + gB[it] + kk, ringb + sbo + 8192 + lo[it]);
        }
    };

    i32x4 acc[4][4];
#pragma unroll
    for (int a = 0; a < 4; ++a)
#pragma unroll
        for (int b = 0; b < 4; ++b) acc[a][b] = (i32x4){0, 0, 0, 0};

    STAGE(0, 0);
    STAGE(16384, BK);
    __builtin_amdgcn_sched_barrier(0);
    asm volatile("s_waitcnt vmcnt(4) lgkmcnt(0)" ::: "memory");
    __builtin_amdgcn_s_barrier();
    __builtin_amdgcn_sched_barrier(0);

    // b128 read: 16B slot = l4 ^ ((l15>>1)&3)  (conflict-free, r10-measured)
    const int rsw = (l15 >> 1) & 3;

#pragma unroll
    for (int kt = 0; kt < NSTEP; ++kt) {
        const int cur = kt % 3;
        if (kt + 2 < NSTEP) STAGE(((kt + 2) % 3) * 16384, (kt + 2) * BK);
        const char* la = ringb + cur * 16384;
        const char* lb = la + 8192;
        i32x4 af[4], bfr[4];
#pragma unroll
        for (int mf = 0; mf < 4; ++mf) {
            int ra = wm * 64 + mf * 16 + l15;
            af[mf] = *(const i32x4*)(la + ra * 64 + ((l4 ^ rsw) << 4));
        }
#pragma unroll
        for (int nf = 0; nf < 4; ++nf) {
            int rb = wn * 64 + nf * 16 + l15;
            bfr[nf] = *(const i32x4*)(lb + rb * 64 + ((l4 ^ rsw) << 4));
        }
        __builtin_amdgcn_s_setprio(1);
#pragma unroll
        for (int mf = 0; mf < 4; ++mf)
#pragma unroll
            for (int nf = 0; nf < 4; ++nf)
                acc[mf][nf] = __builtin_amdgcn_mfma_i32_16x16x64_i8(
                    af[mf], bfr[nf], acc[mf][nf], 0, 0, 0);
        __builtin_amdgcn_s_setprio(0);
        __builtin_amdgcn_sched_barrier(0);
        if (kt + 2 < NSTEP)       asm volatile("s_waitcnt vmcnt(4)" ::: "memory");
        else if (kt + 2 == NSTEP) asm volatile("s_waitcnt vmcnt(0)" ::: "memory");
        if (kt + 1 < NSTEP) {
            __builtin_amdgcn_s_barrier();
            __builtin_amdgcn_sched_barrier(0);
        }
    }
    __syncthreads();   // full drain before LDS overlay

    // ---- epilogue: masked accumulation of (Z, NS2, P1), exp2 domain ----
    float cqz[4] = {0,0,0,0}, cqn[4] = {0,0,0,0}, cqp[4] = {0,0,0,0};
    float* redr = (float*)ringb;              // [2(wn)][128][3]
    float* redc = (float*)(ringb + 16384);    // [2(wm)][128][3]

#pragma unroll
    for (int mf = 0; mf < 4; ++mf) {
#pragma unroll
        for (int r = 0; r < 4; ++r) {
            int rr = wm * 64 + mf * 16 + l4 * 4 + r;
            int rg = row0 + rr;
            int cr = crow[mf * 4 + r];
            float z = 0.f, ns = 0.f, p1 = 0.f;
#pragma unroll
            for (int nf = 0; nf < 4; ++nf) {
                int cc = wn * 64 + nf * 16 + l15;
                float t = fmaf((float)acc[mf][nf][r], QS2L, -SHIFTL);
                float e = exp2f(t);
                bool same = (cr == clscol[cc]);
                bool dg   = (rg == c0 + cc);
                if (!same) { z += e; cqz[nf] += e; }
                else if (!dg) { ns += t; p1 += e; cqn[nf] += t; cqp[nf] += e; }
            }
#pragma unroll
            for (int m = 1; m < 16; m <<= 1) {
                z  += __shfl_xor(z,  m, 16);
                ns += __shfl_xor(ns, m, 16);
                p1 += __shfl_xor(p1, m, 16);
            }
            if (l15 == 0) {
                float* p = &redr[(wn * 128 + rr) * 3];
                p[0] = z; p[1] = ns; p[2] = p1;
            }
        }
    }
    if (!diagblk) {
#pragma unroll
        for (int nf = 0; nf < 4; ++nf) {
            float z = cqz[nf], nsv = cqn[nf], p = cqp[nf];
            z += __shfl_xor(z, 16, 64);  z += __shfl_xor(z, 32, 64);
            nsv += __shfl_xor(nsv, 16, 64); nsv += __shfl_xor(nsv, 32, 64);
            p += __shfl_xor(p, 16, 64);  p += __shfl_xor(p, 32, 64);
            if (l4 == 0) {
                float* pp = &redc[(wm * 128 + wn * 64 + nf * 16 + l15) * 3];
                pp[0] = z; pp[1] = nsv; pp[2] = p;
            }
        }
    }
    __syncthreads();

    if (tid < BT) {                           // row-side partials, slot = bj
#pragma unroll
        for (int q = 0; q < 3; ++q)
            Zpart[q * QS + (size_t)bj * n + row0 + tid] =
                redr[(0 * 128 + tid) * 3 + q] + redr[(1 * 128 + tid) * 3 + q];
    } else if (!diagblk) {                    // col-side partials, slot = bi
        int cc = tid - BT;
#pragma unroll
        for (int q = 0; q < 3; ++q)
            Zpart[q * QS + (size_t)bi * n + c0 + cc] =
                redc[(0 * 128 + cc) * 3 + q] + redc[(1 * 128 + cc) * 3 + q];
    }
}

// ---------------- K3: per-row terms + fused final reduction ----------------
// 32 blocks; each reduces its 256 rows to (loss,cnt) partials; last block
// (ticket atomicAdd) reduces the 32 partials in fixed order -> out[0].
__global__ void k_rowfinal(const float* __restrict__ Zpart,
                           const int* __restrict__ classes,
                           const int* __restrict__ hist,
                           float* __restrict__ partial,
                           int* __restrict__ counter,
                           float* __restrict__ out, int n) {
    const int tid = threadIdx.x;
    const int i   = blockIdx.x * 256 + tid;
    const size_t QS = (size_t)64 * n;
    float z = 0.f, ns = 0.f, p1 = 0.f;
    for (int s = 0; s < 64; ++s) {
        size_t o = (size_t)s * n + i;
        z  += Zpart[o];
        ns += Zpart[QS + o];
        p1 += Zpart[2 * QS + o];
    }
    float c    = (float)(hist[classes[i] & 127] - 1);
    float loss = -ns * LN2 + c * logf(z) + p1 / z;   // ns was in log2 units

    // block reduce (deterministic: shfl tree + fixed wave order)
    __shared__ float sl[4], sc[4];
    __shared__ int lastflag;
    float lsum = loss, csum = c;
#pragma unroll
    for (int m = 1; m < 64; m <<= 1) {
        lsum += __shfl_xor(lsum, m, 64);
        csum += __shfl_xor(csum, m, 64);
    }
    if ((tid & 63) == 0) { sl[tid >> 6] = lsum; sc[tid >> 6] = csum; }
    __syncthreads();
    if (tid == 0) {
        partial[blockIdx.x * 2]     = sl[0] + sl[1] + sl[2] + sl[3];
        partial[blockIdx.x * 2 + 1] = sc[0] + sc[1] + sc[2] + sc[3];
        __threadfence();                      // publish partials (device scope)
        int old = atomicAdd(counter, 1);
        lastflag = (old == (int)gridDim.x - 1);
    }
    __syncthreads();
    if (lastflag) {
        __threadfence();                      // acquire all partials
        if (tid < 64) {
            float L = 0.f, C = 0.f;
            if (tid < 32) { L = partial[tid * 2]; C = partial[tid * 2 + 1]; }
#pragma unroll
            for (int m = 1; m < 32; m <<= 1) {
                L += __shfl_xor(L, m, 64);
                C += __shfl_xor(C, m, 64);
            }
            if (tid == 0) out[0] = (C > 0.f) ? L / C : 0.f;
        }
    }
}

extern "C" void kernel_launch(void* const* d_in, const int* in_sizes, int n_in,
                              void* d_out, int out_size, void* d_ws, size_t ws_size,
                              hipStream_t stream) {
    const float* emb     = (const float*)d_in[0];
    const int*   classes = (const int*)d_in[1];
    float*       out     = (float*)d_out;
    const int n  = in_sizes[1];               // 8192
    const int nb = n / BT;                    // 64
    const int npairs = nb * (nb + 1) / 2;     // 2080

    uchar*  normed  = (uchar*)d_ws;                                    // 4 MB
    float*  Zpart   = (float*)((char*)d_ws + (size_t)n * D);           // 6 MB
    float*  partial = Zpart + (size_t)3 * 64 * n;                      // 64 floats
    int*    hist    = (int*)(partial + 64);                            // 512 B
    int*    counter = hist + 128;                                      // 4 B

    hipMemsetAsync(counter, 0, sizeof(int), stream);
    k_normalize<<<n / 4, 256, 0, stream>>>(emb, classes, normed, hist, n);
    k_zgemm<<<npairs, 256, 0, stream>>>(normed, classes, Zpart, n, nb, npairs);
    k_rowfinal<<<n / 256, 256, 0, stream>>>(Zpart, classes, hist, partial, counter, out, n);
}

// Round 19
// 75.601 us; speedup vs baseline: 1.2404x; 1.0789x over previous
//
#include <hip/hip_runtime.h>
#include <hip/hip_bf16.h>

// InfoNCE loss, N=8192 D=512 C=128.
// Fixed-shift softmax (M=10): t_ij = s_ij/tau - 10 in [-20, 0].
//   Z_i  = sum_{class!=} e^{t_ij}
//   term = -t_p + log(Z + e^{t_p}) ~= -t_p + logZ + e^{t_p}/Z
// r18 -> r19: revert r18's fusion (tail 23.0 -> 26.6, net loss) to r14's
// separate rowterms/final. zgemm = r14 sync discipline + r17 A-in-regs:
// A strip (wave w rows w*32..+32, ALL of K) in 64 VGPR -> A staging and
// A LDS reads leave the window; window widens to BK=128 (4 windows, half
// the barrier overhead, 32 MFMA + 16 B ds_reads/wave/window); B-only
// ring-3 = 48KB -> still 3 blocks/CU; vmcnt stays COUNTED (4/0 tail only).
// This is r15's BK=128 without its failure modes (64KB LDS, mid-loop drain).
// vmcnt ledger incl. A-prologue: prologue vmcnt(4) = areg+stage0 drained,
// stage1 in flight; per-window issue-4/wait-4; kt=2 vmcnt(0).

constexpr int   D      = 512;
constexpr int   BT     = 128;
constexpr int   BK     = 128;        // bytes (i8 elems) per window
constexpr int   NSTEP  = D / BK;     // 4
constexpr float SHIFTL = 14.4269504088896340f;        // 10 * log2(e)
constexpr float QS2L   = 10.0f * 1.4426950408889634f / 16129.0f; // /tau/127^2*log2e
constexpr float LN2    = 0.6931471805599453f;

typedef __attribute__((ext_vector_type(4))) int i32x4;
typedef unsigned char uchar;
typedef unsigned long ulong_t;

__device__ inline void gload_lds16(const uchar* g, void* l) {
    __builtin_amdgcn_global_load_lds(
        (const __attribute__((address_space(1))) void*)g,
        (__attribute__((address_space(3))) void*)l, 16, 0, 0);
}

// ---------------- K1: L2-normalize rows, f32 -> i8 (+hist in block 0) ----
__global__ void k_normalize(const float* __restrict__ emb,
                            const int* __restrict__ classes,
                            uchar* __restrict__ normed,
                            int* __restrict__ hist, int n) {
    if (blockIdx.x == 0) {
        __shared__ int h[128];
        if (threadIdx.x < 128) h[threadIdx.x] = 0;
        __syncthreads();
        for (int i = threadIdx.x; i < n; i += 256)
            atomicAdd(&h[classes[i] & 127], 1);
        __syncthreads();
        if (threadIdx.x < 128) hist[threadIdx.x] = h[threadIdx.x];
    }
    int row  = blockIdx.x * 4 + (threadIdx.x >> 6);
    int lane = threadIdx.x & 63;
    if (row >= n) return;
    const float4* src = (const float4*)(emb + (size_t)row * D);
    float4 a = src[lane * 2];
    float4 b = src[lane * 2 + 1];
    float ss = a.x*a.x + a.y*a.y + a.z*a.z + a.w*a.w
             + b.x*b.x + b.y*b.y + b.z*b.z + b.w*b.w;
#pragma unroll
    for (int m = 1; m < 64; m <<= 1) ss += __shfl_xor(ss, m, 64);
    float sc = 127.0f / fmaxf(sqrtf(ss), 1e-12f);
    union { signed char c[8]; ulong_t u; } o;
    float v[8] = {a.x, a.y, a.z, a.w, b.x, b.y, b.z, b.w};
#pragma unroll
    for (int k = 0; k < 8; ++k) {
        int q = (int)rintf(v[k] * sc);
        q = q > 127 ? 127 : (q < -127 ? -127 : q);
        o.c[k] = (signed char)q;
    }
    *(ulong_t*)&normed[(size_t)row * D + lane * 8] = o.u;
}

// ---------------- K2: i8 GEMM, A-in-regs + B ring-3, BK=128 ---------------
// Zpart: plane q in 0..2 (Z,NS2,P1), each [64 slots][n rows].
__global__ __launch_bounds__(256, 3) void k_zgemm(
    const uchar* __restrict__ normed, const int* __restrict__ classes,
    float* __restrict__ Zpart, int n, int nb, int npairs) {
    __shared__ char ring[3][16384];           // B-only: 3 windows x 16KB
    __shared__ int clsrow[BT], clscol[BT];

    const int tid  = threadIdx.x;
    const int lane = tid & 63;
    const int w    = tid >> 6;                // wave owns rows w*32..+32
    const int l15  = lane & 15, l4 = lane >> 4;
    const size_t QS = (size_t)64 * n;

    // XCD-chunked bijective swizzle
    int q8 = npairs >> 3, r8 = npairs & 7;
    int xcd = blockIdx.x & 7, off = blockIdx.x >> 3;
    int orig = (xcd < r8 ? xcd * (q8 + 1) : r8 * (q8 + 1) + (xcd - r8) * q8) + off;

    // orig -> (bi,bj) via 8x8 supertile walk
    const int sgrid = nb >> 3;               // 8
    int idx = orig, si = 0;
    for (;;) { int rc = 36 + (sgrid - 1 - si) * 64; if (idx < rc) break; idx -= rc; ++si; }
    int bi, bj;
    if (idx < 36) { int u = 0, rem = 8; while (idx >= rem) { idx -= rem; ++u; --rem; }
                    bi = si * 8 + u; bj = si * 8 + u + idx; }
    else { idx -= 36; int sj = si + 1 + (idx >> 6); int v = idx & 63;
           bi = si * 8 + (v >> 3); bj = sj * 8 + (v & 7); }
    const int row0 = bi * BT, c0 = bj * BT;
    const bool diagblk = (bi == bj);

    if (tid < BT) clsrow[tid] = classes[row0 + tid];
    else          clscol[tid - BT] = classes[c0 + tid - BT];

    // ---- A strip into registers (issued FIRST; drained by prologue wait) --
    i32x4 areg[2][8];
#pragma unroll
    for (int rg = 0; rg < 2; ++rg)
#pragma unroll
        for (int kf = 0; kf < 8; ++kf)
            areg[rg][kf] = *(const i32x4*)&normed[
                (size_t)(row0 + w * 32 + rg * 16 + l15) * D + kf * 64 + l4 * 16];

    // B staging: per 8KB half = 8 chunks of 16 cols x 64B; wave w owns
    // chunks {2w,2w+1}. Source 16B slot pre-swizzled (involution, r10).
    const int src16 = (lane & 3) ^ ((lane >> 3) & 3);
    size_t gB[2]; int lo[2];
#pragma unroll
    for (int it = 0; it < 2; ++it) {
        int chunk = w * 2 + it;
        int row   = chunk * 16 + (lane >> 2);
        gB[it] = (size_t)(c0 + row) * D + src16 * 16;
        lo[it] = chunk * 1024;
    }
    char* ringb = &ring[0][0];

    auto STAGE = [&](int sbo, int kk) {       // kk = window * 128 (bytes)
#pragma unroll
        for (int h = 0; h < 2; ++h)
#pragma unroll
            for (int it = 0; it < 2; ++it)
                gload_lds16(normed + gB[it] + kk + h * 64,
                            ringb + sbo + h * 8192 + lo[it]);
    };

    i32x4 acc[2][8];
#pragma unroll
    for (int rg = 0; rg < 2; ++rg)
#pragma unroll
        for (int cf = 0; cf < 8; ++cf) acc[rg][cf] = (i32x4){0, 0, 0, 0};

    STAGE(0, 0);
    STAGE(16384, BK);
    __builtin_amdgcn_sched_barrier(0);
    asm volatile("s_waitcnt vmcnt(4) lgkmcnt(0)" ::: "memory");
    __builtin_amdgcn_s_barrier();
    __builtin_amdgcn_sched_barrier(0);

    // b128 B read: 16B slot = l4 ^ ((rb>>1)&3), rb>>1 ~ l15>>1 (0 conflicts)
    const int rsw = (l15 >> 1) & 3;

#pragma unroll
    for (int kt = 0; kt < NSTEP; ++kt) {
        const int cur = kt % 3;
        if (kt + 2 < NSTEP) STAGE(((kt + 2) % 3) * 16384, (kt + 2) * BK);
        const char* base = ringb + cur * 16384;
#pragma unroll
        for (int h = 0; h < 2; ++h) {
            const char* lb = base + h * 8192;
            i32x4 bfr[8];
#pragma unroll
            for (int cf = 0; cf < 8; ++cf) {
                int rb = cf * 16 + l15;
                bfr[cf] = *(const i32x4*)(lb + rb * 64 + ((l4 ^ rsw) << 4));
            }
            __builtin_amdgcn_s_setprio(1);
#pragma unroll
            for (int rg = 0; rg < 2; ++rg)
#pragma unroll
                for (int cf = 0; cf < 8; ++cf)
                    acc[rg][cf] = __builtin_amdgcn_mfma_i32_16x16x64_i8(
                        areg[rg][kt * 2 + h], bfr[cf], acc[rg][cf], 0, 0, 0);
            __builtin_amdgcn_s_setprio(0);
        }
        __builtin_amdgcn_sched_barrier(0);
        if (kt + 2 < NSTEP)       asm volatile("s_waitcnt vmcnt(4)" ::: "memory");
        else if (kt + 2 == NSTEP) asm volatile("s_waitcnt vmcnt(0)" ::: "memory");
        if (kt + 1 < NSTEP) {
            __builtin_amdgcn_s_barrier();
            __builtin_amdgcn_sched_barrier(0);
        }
    }
    __syncthreads();   // full drain before LDS overlay

    // ---- epilogue (exp2 domain): r17 layout ----
    float* redr = (float*)ringb;              // [128 rr][3] = 1.5 KB
    float* redc = (float*)(ringb + 2048);     // [4 w][128 cc][3] = 6 KB

    int crow[2][4];
#pragma unroll
    for (int rg = 0; rg < 2; ++rg)
#pragma unroll
        for (int r = 0; r < 4; ++r)
            crow[rg][r] = clsrow[w * 32 + rg * 16 + l4 * 4 + r];
    int ccv[8];
#pragma unroll
    for (int cf = 0; cf < 8; ++cf) ccv[cf] = clscol[cf * 16 + l15];

    float cq[8][3];
#pragma unroll
    for (int cf = 0; cf < 8; ++cf) cq[cf][0] = cq[cf][1] = cq[cf][2] = 0.f;

#pragma unroll
    for (int rg = 0; rg < 2; ++rg) {
#pragma unroll
        for (int r = 0; r < 4; ++r) {
            int rr = w * 32 + rg * 16 + l4 * 4 + r;
            int cr = crow[rg][r];
            float z = 0.f, ns = 0.f, p1 = 0.f;
#pragma unroll
            for (int cf = 0; cf < 8; ++cf) {
                int cc = cf * 16 + l15;
                float tt = fmaf((float)acc[rg][cf][r], QS2L, -SHIFTL);
                float e = exp2f(tt);
                bool same = (cr == ccv[cf]);
                bool dg   = diagblk && (rr == cc);
                if (!same) { z += e; cq[cf][0] += e; }
                else if (!dg) { ns += tt; p1 += e; cq[cf][1] += tt; cq[cf][2] += e; }
            }
#pragma unroll
            for (int m = 1; m < 16; m <<= 1) {
                z  += __shfl_xor(z,  m, 16);
                ns += __shfl_xor(ns, m, 16);
                p1 += __shfl_xor(p1, m, 16);
            }
            if (l15 == 0) {
                redr[rr * 3 + 0] = z;
                redr[rr * 3 + 1] = ns;
                redr[rr * 3 + 2] = p1;
            }
        }
    }
    if (!diagblk) {
#pragma unroll
        for (int cf = 0; cf < 8; ++cf) {
            float z = cq[cf][0], nsv = cq[cf][1], p = cq[cf][2];
            z += __shfl_xor(z, 16, 64);  z += __shfl_xor(z, 32, 64);
            nsv += __shfl_xor(nsv, 16, 64); nsv += __shfl_xor(nsv, 32, 64);
            p += __shfl_xor(p, 16, 64);  p += __shfl_xor(p, 32, 64);
            if (l4 == 0) {
                float* pp = &redc[(w * 128 + cf * 16 + l15) * 3];
                pp[0] = z; pp[1] = nsv; pp[2] = p;
            }
        }
    }
    __syncthreads();

    if (tid < BT) {                           // row-side partials, slot = bj
#pragma unroll
        for (int q = 0; q < 3; ++q)
            Zpart[q * QS + (size_t)bj * n + row0 + tid] = redr[tid * 3 + q];
    } else if (!diagblk) {                    // col-side partials, slot = bi
        int cc = tid - BT;
#pragma unroll
        for (int q = 0; q < 3; ++q)
            Zpart[q * QS + (size_t)bi * n + c0 + cc] =
                redc[(0 * 128 + cc) * 3 + q] + redc[(1 * 128 + cc) * 3 + q] +
                redc[(2 * 128 + cc) * 3 + q] + redc[(3 * 128 + cc) * 3 + q];
    }
}

// ---------------- K3: per-row closed-form terms ----------------
__global__ void k_rowterms(const float* __restrict__ Zpart,
                           const int* __restrict__ classes,
                           const int* __restrict__ hist,
                           float* __restrict__ rowloss,
                           float* __restrict__ rowcnt, int n) {
    int i = blockIdx.x * 256 + threadIdx.x;
    if (i >= n) return;
    const size_t QS = (size_t)64 * n;
    float z = 0.f, ns = 0.f, p1 = 0.f;
    for (int s = 0; s < 64; ++s) {
        size_t o = (size_t)s * n + i;
        z  += Zpart[o];
        ns += Zpart[QS + o];
        p1 += Zpart[2 * QS + o];
    }
    float c = (float)(hist[classes[i] & 127] - 1);
    rowloss[i] = -ns * LN2 + c * logf(z) + p1 / z;   // ns was in log2 units
    rowcnt[i]  = c;
}

// ---------------- K4: final deterministic reduction ----------------
__global__ void k_final(const float* __restrict__ rowloss,
                        const float* __restrict__ rowcnt,
                        float* __restrict__ out, int n) {
    __shared__ float sl[1024];
    __shared__ float sc[1024];
    float l = 0.f, c = 0.f;
    for (int i = threadIdx.x; i < n; i += 1024) {
        l += rowloss[i];
        c += rowcnt[i];
    }
    sl[threadIdx.x] = l;
    sc[threadIdx.x] = c;
    __syncthreads();
    for (int s = 512; s > 0; s >>= 1) {
        if (threadIdx.x < s) {
            sl[threadIdx.x] += sl[threadIdx.x + s];
            sc[threadIdx.x] += sc[threadIdx.x + s];
        }
        __syncthreads();
    }
    if (threadIdx.x == 0)
        out[0] = (sc[0] > 0.f) ? sl[0] / sc[0] : 0.f;
}

extern "C" void kernel_launch(void* const* d_in, const int* in_sizes, int n_in,
                              void* d_out, int out_size, void* d_ws, size_t ws_size,
                              hipStream_t stream) {
    const float* emb     = (const float*)d_in[0];
    const int*   classes = (const int*)d_in[1];
    float*       out     = (float*)d_out;
    const int n  = in_sizes[1];               // 8192
    const int nb = n / BT;                    // 64
    const int npairs = nb * (nb + 1) / 2;     // 2080

    uchar*  normed  = (uchar*)d_ws;                                    // 4 MB
    float*  Zpart   = (float*)((char*)d_ws + (size_t)n * D);           // 6 MB
    float*  rowloss = Zpart + (size_t)3 * 64 * n;
    float*  rowcnt  = rowloss + n;
    int*    hist    = (int*)(rowcnt + n);                              // 512 B

    k_normalize<<<n / 4, 256, 0, stream>>>(emb, classes, normed, hist, n);
    k_zgemm<<<npairs, 256, 0, stream>>>(normed, classes, Zpart, n, nb, npairs);
    k_rowterms<<<(n + 255) / 256, 256, 0, stream>>>(Zpart, classes, hist, rowloss, rowcnt, n);
    k_final<<<1, 1024, 0, stream>>>(rowloss, rowcnt, out, n);
}